// Round 3
// baseline (81.096 us; speedup 1.0000x reference)
//
#include <hip/hip_runtime.h>
#include <cstddef>

#define B_    8
#define T_EN_ 512
#define T_DE_ 128
#define D_    512
#define U_    256

// tanh(x) = 1 - 2/(exp2(C*x)+1), C = 2*log2(e)
#define TANH_C 2.8853900817779268f
#define L2E_   1.4426950408889634f
#define TANH_CLAMP 0.99999994f

__device__ __forceinline__ float fast_tanh_clamped(float x) {
  const float e = __builtin_amdgcn_exp2f(x * TANH_C);
  float t = fmaf(-2.0f, __builtin_amdgcn_rcpf(e + 1.0f), 1.0f);
  return fminf(fmaxf(t, -TANH_CLAMP), TANH_CLAMP);
}

// ---------------------------------------------------------------------------
// K1: fused projections + tanh.
//  blocks [0,512):  Et[b][u][i] = tanh(en_b @ w_en)^T, tile 32u x 64i
//  blocks [512,640): de_t[jg][u] = tanh(de @ w_de),    tile 32j x 64u
// 128 threads (2 waves), 4x4 per thread, K-step 32, reg-prefetch staging.
// ---------------------------------------------------------------------------
__global__ __launch_bounds__(128) void proj_tanh_kernel(
    const float* __restrict__ en, const float* __restrict__ de,
    const float* __restrict__ w_en, const float* __restrict__ w_de,
    float* __restrict__ Et, float* __restrict__ de_t) {
  __shared__ float Rs[32][36];   // [k][row]  (rows of the output tile)
  __shared__ float Cs[32][68];   // [k][col]  (cols of the output tile)

  const int tid = threadIdx.x;
  const int bx = blockIdx.x;
  const bool en_branch = bx < 512;

  const int ty = tid >> 4;   // 0..7  -> rows ty*4..+3
  const int tx = tid & 15;   // 0..15 -> cols tx*4..+3

  int b = 0, u0 = 0, i0 = 0, jg0 = 0, u0c = 0;
  if (en_branch) {
    b = bx >> 6; u0 = ((bx >> 3) & 7) * 32; i0 = (bx & 7) * 64;
  } else {
    const int y = bx - 512;
    jg0 = (y >> 2) * 32; u0c = (y & 3) * 64;
  }

  // loader indices
  const int dk = tid >> 2, dq = tid & 3;    // direct (row-major) stage
  const int ti = tid & 63, th = tid >> 6;   // en: C transpose stage
  const int tj = tid & 31, t4 = tid >> 5;   // de: R transpose stage

  float4 rA, rB, cA, cB, cC, cD;

#define LOAD_STEP(K0)                                                          \
  if (en_branch) {                                                             \
    rA = *(const float4*)(w_en + (size_t)((K0) + dk) * U_ + u0 + dq * 4);      \
    rB = *(const float4*)(w_en + (size_t)((K0) + dk) * U_ + u0 + dq * 4 + 16); \
    const float* ep = en + ((size_t)b * T_EN_ + i0 + ti) * D_ + (K0) + th * 16;\
    cA = *(const float4*)(ep + 0);                                             \
    cB = *(const float4*)(ep + 4);                                             \
    cC = *(const float4*)(ep + 8);                                             \
    cD = *(const float4*)(ep + 12);                                            \
  } else {                                                                     \
    const float* dp = de + (size_t)(jg0 + tj) * D_ + (K0) + t4 * 8;            \
    rA = *(const float4*)(dp + 0);                                             \
    rB = *(const float4*)(dp + 4);                                             \
    cA = *(const float4*)(w_de + (size_t)((K0) + dk) * U_ + u0c + dq * 4);     \
    cB = *(const float4*)(w_de + (size_t)((K0) + dk) * U_ + u0c + (dq + 4) * 4);\
    cC = *(const float4*)(w_de + (size_t)((K0) + dk) * U_ + u0c + (dq + 8) * 4);\
    cD = *(const float4*)(w_de + (size_t)((K0) + dk) * U_ + u0c + (dq + 12) * 4);\
  }

#define STORE_STEP                                                             \
  if (en_branch) {                                                             \
    *(float4*)&Rs[dk][dq * 4] = rA;                                            \
    *(float4*)&Rs[dk][dq * 4 + 16] = rB;                                       \
    Cs[th * 16 + 0][ti] = cA.x;  Cs[th * 16 + 1][ti] = cA.y;                   \
    Cs[th * 16 + 2][ti] = cA.z;  Cs[th * 16 + 3][ti] = cA.w;                   \
    Cs[th * 16 + 4][ti] = cB.x;  Cs[th * 16 + 5][ti] = cB.y;                   \
    Cs[th * 16 + 6][ti] = cB.z;  Cs[th * 16 + 7][ti] = cB.w;                   \
    Cs[th * 16 + 8][ti] = cC.x;  Cs[th * 16 + 9][ti] = cC.y;                   \
    Cs[th * 16 + 10][ti] = cC.z; Cs[th * 16 + 11][ti] = cC.w;                  \
    Cs[th * 16 + 12][ti] = cD.x; Cs[th * 16 + 13][ti] = cD.y;                  \
    Cs[th * 16 + 14][ti] = cD.z; Cs[th * 16 + 15][ti] = cD.w;                  \
  } else {                                                                     \
    Rs[t4 * 8 + 0][tj] = rA.x;   Rs[t4 * 8 + 1][tj] = rA.y;                    \
    Rs[t4 * 8 + 2][tj] = rA.z;   Rs[t4 * 8 + 3][tj] = rA.w;                    \
    Rs[t4 * 8 + 4][tj] = rB.x;   Rs[t4 * 8 + 5][tj] = rB.y;                    \
    Rs[t4 * 8 + 6][tj] = rB.z;   Rs[t4 * 8 + 7][tj] = rB.w;                    \
    *(float4*)&Cs[dk][dq * 4] = cA;                                            \
    *(float4*)&Cs[dk][(dq + 4) * 4] = cB;                                      \
    *(float4*)&Cs[dk][(dq + 8) * 4] = cC;                                      \
    *(float4*)&Cs[dk][(dq + 12) * 4] = cD;                                     \
  }

  float acc[4][4] = {};

  LOAD_STEP(0)
  for (int k0 = 0; k0 < D_; k0 += 32) {
    __syncthreads();             // prior inner-loop readers done
    STORE_STEP                   // waits on this step's loads
    if (k0 + 32 < D_) { LOAD_STEP(k0 + 32) }  // next-step loads hide under inner
    __syncthreads();

    #pragma unroll
    for (int k = 0; k < 32; ++k) {
      const float4 a4 = *(const float4*)&Rs[k][ty * 4];
      const float4 b4 = *(const float4*)&Cs[k][tx * 4];
      const float ar[4] = {a4.x, a4.y, a4.z, a4.w};
      const float br[4] = {b4.x, b4.y, b4.z, b4.w};
      #pragma unroll
      for (int m = 0; m < 4; ++m)
        #pragma unroll
        for (int n = 0; n < 4; ++n)
          acc[m][n] = fmaf(ar[m], br[n], acc[m][n]);
    }
  }

  float* Y;
  size_t ld;
  int rbase, cbase;
  if (en_branch) { Y = Et + (size_t)b * U_ * T_EN_; ld = T_EN_; rbase = u0;  cbase = i0; }
  else           { Y = de_t;                        ld = U_;    rbase = jg0; cbase = u0c; }

  #pragma unroll
  for (int m = 0; m < 4; ++m) {
    float4 o;
    o.x = fast_tanh_clamped(acc[m][0]);
    o.y = fast_tanh_clamped(acc[m][1]);
    o.z = fast_tanh_clamped(acc[m][2]);
    o.w = fast_tanh_clamped(acc[m][3]);
    *(float4*)(Y + (size_t)(rbase + ty * 4 + m) * ld + cbase + tx * 4) = o;
  }
#undef LOAD_STEP
#undef STORE_STEP
}

// ---------------------------------------------------------------------------
// K2: mu[b,j,i] = sum_u (A + E)*nu / (1 + A*E), A=de_t[j,u], E=Et[b,u,i],
//     then out[b,j,:] = softmax(mu + (mask-1)*1e6).
// 256 blocks (b x 32 j-quads), 512 threads = 8 waves.
// wave w: j = jq (w&3), i-half h (w>>2); lane owns i = h*256 + lane*4 + 0..3.
// No cross-lane ops in the u-loop; A/nu are wave-uniform (scalar path).
// ---------------------------------------------------------------------------
__global__ __launch_bounds__(512) void attn_mu_softmax_kernel(
    const float* __restrict__ Et, const float* __restrict__ de_t,
    const float* __restrict__ nu, const int* __restrict__ mask,
    float* __restrict__ out) {
  __shared__ float red_s[2][4][2];   // [max|sum][jq][h]

  const int tid  = threadIdx.x;
  const int lane = tid & 63;
  const int w    = __builtin_amdgcn_readfirstlane(tid >> 6);  // 0..7, uniform
  const int jq   = w & 3;
  const int h    = w >> 2;
  const int b    = blockIdx.x >> 5;
  const int j    = (blockIdx.x & 31) * 4 + jq;

  const float* __restrict__ Arow  = de_t + (size_t)(b * T_DE_ + j) * U_;
  const float* __restrict__ nuP   = nu;
  const float* __restrict__ Ebase = Et + (size_t)b * U_ * T_EN_ + h * 256 + lane * 4;

  float acc0 = 0.f, acc1 = 0.f, acc2 = 0.f, acc3 = 0.f;

#define LOADC(BUF, U0)                                                   \
  { _Pragma("unroll")                                                    \
    for (int q = 0; q < 8; ++q)                                          \
      BUF[q] = *(const float4*)(Ebase + (size_t)((U0) + q) * T_EN_); }

#define COMP(BUF, U0)                                                    \
  { _Pragma("unroll")                                                    \
    for (int q = 0; q < 8; ++q) {                                        \
      const float A  = Arow[(U0) + q];                                   \
      const float nv = nuP[(U0) + q];                                    \
      const float An = A * nv;                                           \
      acc0 = fmaf(fmaf(nv, BUF[q].x, An),                                \
                  __builtin_amdgcn_rcpf(fmaf(A, BUF[q].x, 1.0f)), acc0); \
      acc1 = fmaf(fmaf(nv, BUF[q].y, An),                                \
                  __builtin_amdgcn_rcpf(fmaf(A, BUF[q].y, 1.0f)), acc1); \
      acc2 = fmaf(fmaf(nv, BUF[q].z, An),                                \
                  __builtin_amdgcn_rcpf(fmaf(A, BUF[q].z, 1.0f)), acc2); \
      acc3 = fmaf(fmaf(nv, BUF[q].w, An),                                \
                  __builtin_amdgcn_rcpf(fmaf(A, BUF[q].w, 1.0f)), acc3); } }

  float4 Ea[8], Eb[8];
  LOADC(Ea, 0)
  for (int u0 = 0; u0 < U_; u0 += 16) {
    LOADC(Eb, u0 + 8)
    COMP(Ea, u0)
    if (u0 + 16 < U_) LOADC(Ea, u0 + 16)
    COMP(Eb, u0 + 8)
  }
#undef LOADC
#undef COMP

  // masked softmax over i (one j per wave; combine the two i-half waves)
  const int4 mk = *(const int4*)(mask + b * T_EN_ + h * 256 + lane * 4);
  float v0 = fmaf((float)mk.x - 1.0f, 1.0e6f, acc0);
  float v1 = fmaf((float)mk.y - 1.0f, 1.0e6f, acc1);
  float v2 = fmaf((float)mk.z - 1.0f, 1.0e6f, acc2);
  float v3 = fmaf((float)mk.w - 1.0f, 1.0e6f, acc3);

  float mx = fmaxf(fmaxf(v0, v1), fmaxf(v2, v3));
  #pragma unroll
  for (int off = 32; off; off >>= 1) mx = fmaxf(mx, __shfl_xor(mx, off, 64));
  if (lane == 0) red_s[0][jq][h] = mx;
  __syncthreads();
  const float M = fmaxf(red_s[0][jq][0], red_s[0][jq][1]);

  const float e0 = __builtin_amdgcn_exp2f((v0 - M) * L2E_);
  const float e1 = __builtin_amdgcn_exp2f((v1 - M) * L2E_);
  const float e2 = __builtin_amdgcn_exp2f((v2 - M) * L2E_);
  const float e3 = __builtin_amdgcn_exp2f((v3 - M) * L2E_);
  float s = (e0 + e1) + (e2 + e3);
  #pragma unroll
  for (int off = 32; off; off >>= 1) s += __shfl_xor(s, off, 64);
  if (lane == 0) red_s[1][jq][h] = s;
  __syncthreads();
  const float S = red_s[1][jq][0] + red_s[1][jq][1];
  const float inv = __builtin_amdgcn_rcpf(S);

  const float4 o = make_float4(e0 * inv, e1 * inv, e2 * inv, e3 * inv);
  *(float4*)(out + (size_t)(b * T_DE_ + j) * T_EN_ + h * 256 + lane * 4) = o;
}

// ---------------------------------------------------------------------------
extern "C" void kernel_launch(void* const* d_in, const int* in_sizes, int n_in,
                              void* d_out, int out_size, void* d_ws, size_t ws_size,
                              hipStream_t stream) {
  const float* en   = (const float*)d_in[0];   // [B, T_EN, D]
  const float* de   = (const float*)d_in[1];   // [B, T_DE, D]
  const int*   mask = (const int*)d_in[2];     // [B, T_EN]
  const float* w_en = (const float*)d_in[3];   // [D, U]
  const float* w_de = (const float*)d_in[4];   // [D, U]
  const float* nu   = (const float*)d_in[5];   // [U, 1]
  float* out = (float*)d_out;                  // [B, T_DE, T_EN]

  float* Et   = (float*)d_ws;                          // tanh(en@w_en)^T: [B][U][T_EN], 4 MB
  float* de_t = Et + (size_t)B_ * U_ * T_EN_;          // tanh(de@w_de):   [B*T_DE][U], 1 MB

  proj_tanh_kernel<<<dim3(640), 128, 0, stream>>>(en, de, w_en, w_de, Et, de_t);
  attn_mu_softmax_kernel<<<dim3(B_ * (T_DE_ / 4)), 512, 0, stream>>>(Et, de_t, nu, mask, out);
}

// Round 4
// 71.954 us; speedup vs baseline: 1.1271x; 1.1271x over previous
//
#include <hip/hip_runtime.h>
#include <cstddef>

#define B_    8
#define T_EN_ 512
#define T_DE_ 128
#define D_    512
#define U_    256

// tanh(x) = 1 - 2/(exp2(C*x)+1), C = 2*log2(e)
#define TANH_C 2.8853900817779268f
#define L2E_   1.4426950408889634f
#define TANH_CLAMP 0.99999994f

__device__ __forceinline__ float fast_tanh_clamped(float x) {
  const float e = __builtin_amdgcn_exp2f(x * TANH_C);
  float t = fmaf(-2.0f, __builtin_amdgcn_rcpf(e + 1.0f), 1.0f);
  return fminf(fmaxf(t, -TANH_CLAMP), TANH_CLAMP);
}

// ---------------------------------------------------------------------------
// K1: fused projections + tanh. Hybrid-operand GEMM:
//   w operand: per-lane coalesced b64 global loads (L2-hot, lane owns 2 u's)
//   x operand: wave-uniform LDS broadcast (block stages its 16 rows once)
// Block = 256 thr (4 waves), covers 16 rows x all 256 u.
//   wave: u0 = (w&1)*128, rows r0 = (w>>1)*8. acc = 2u x 8rows per lane.
// Grid: blocks [0,256) -> en rows (16 i), writes Et[b][u][i] (b128 scatter);
//       blocks [256,320) -> de rows (16 j), writes de_t[j][u] (coalesced).
// No __syncthreads in the K-loop; w double-buffered in registers.
// ---------------------------------------------------------------------------
__global__ __launch_bounds__(256) void proj_tanh_kernel(
    const float* __restrict__ en, const float* __restrict__ de,
    const float* __restrict__ w_en, const float* __restrict__ w_de,
    float* __restrict__ Et, float* __restrict__ de_t) {
  __shared__ float xs[16 * D_];   // 32 KB staged activation rows

  const int tid = threadIdx.x;
  const int bx = blockIdx.x;
  const bool enb = bx < 256;

  const float *X, *W;
  int b = 0, i0 = 0, j0 = 0;
  if (enb) {
    b = bx >> 5; i0 = (bx & 31) * 16;
    X = en + ((size_t)b * T_EN_ + i0) * D_;
    W = w_en;
  } else {
    j0 = (bx - 256) * 16;
    X = de + (size_t)j0 * D_;
    W = w_de;
  }

  // Stage 16 contiguous rows (32 KB) as a flat coalesced copy.
  {
    const float4* Xv = (const float4*)X;
    float4* Sv = (float4*)xs;
    #pragma unroll
    for (int q = 0; q < 8; ++q) Sv[tid + 256 * q] = Xv[tid + 256 * q];
  }
  __syncthreads();

  const int lane = tid & 63;
  const int wv = __builtin_amdgcn_readfirstlane(tid >> 6);  // 0..3
  const int u0 = (wv & 1) * 128;
  const int r0 = (wv >> 1) * 8;

  const float* wp = W + u0 + 2 * lane;
  float2 wc[8], wn[8];
  #pragma unroll
  for (int q = 0; q < 8; ++q) wc[q] = *(const float2*)(wp + (size_t)q * U_);

  float a0[8] = {};   // u = u0 + 2*lane
  float a1[8] = {};   // u = u0 + 2*lane + 1

  for (int d0 = 0; d0 < D_; d0 += 8) {
    if (d0 + 8 < D_) {
      #pragma unroll
      for (int q = 0; q < 8; ++q)
        wn[q] = *(const float2*)(wp + (size_t)(d0 + 8 + q) * U_);
    }
    #pragma unroll
    for (int r = 0; r < 8; ++r) {
      const float4 xa = *(const float4*)(xs + (r0 + r) * D_ + d0);
      const float4 xb = *(const float4*)(xs + (r0 + r) * D_ + d0 + 4);
      a0[r] = fmaf(xa.x, wc[0].x, a0[r]);  a1[r] = fmaf(xa.x, wc[0].y, a1[r]);
      a0[r] = fmaf(xa.y, wc[1].x, a0[r]);  a1[r] = fmaf(xa.y, wc[1].y, a1[r]);
      a0[r] = fmaf(xa.z, wc[2].x, a0[r]);  a1[r] = fmaf(xa.z, wc[2].y, a1[r]);
      a0[r] = fmaf(xa.w, wc[3].x, a0[r]);  a1[r] = fmaf(xa.w, wc[3].y, a1[r]);
      a0[r] = fmaf(xb.x, wc[4].x, a0[r]);  a1[r] = fmaf(xb.x, wc[4].y, a1[r]);
      a0[r] = fmaf(xb.y, wc[5].x, a0[r]);  a1[r] = fmaf(xb.y, wc[5].y, a1[r]);
      a0[r] = fmaf(xb.z, wc[6].x, a0[r]);  a1[r] = fmaf(xb.z, wc[6].y, a1[r]);
      a0[r] = fmaf(xb.w, wc[7].x, a0[r]);  a1[r] = fmaf(xb.w, wc[7].y, a1[r]);
    }
    #pragma unroll
    for (int q = 0; q < 8; ++q) wc[q] = wn[q];
  }

  // tanh epilogue
  float t0[8], t1[8];
  #pragma unroll
  for (int r = 0; r < 8; ++r) {
    t0[r] = fast_tanh_clamped(a0[r]);
    t1[r] = fast_tanh_clamped(a1[r]);
  }

  if (enb) {
    // lane's row u holds 8 contiguous i's: i0+r0 .. i0+r0+7  -> 2 b128 stores/row
    const int uA = u0 + 2 * lane;
    float* pA = Et + ((size_t)b * U_ + uA) * T_EN_ + i0 + r0;
    float* pB = pA + T_EN_;   // u + 1
    *(float4*)(pA + 0) = make_float4(t0[0], t0[1], t0[2], t0[3]);
    *(float4*)(pA + 4) = make_float4(t0[4], t0[5], t0[6], t0[7]);
    *(float4*)(pB + 0) = make_float4(t1[0], t1[1], t1[2], t1[3]);
    *(float4*)(pB + 4) = make_float4(t1[4], t1[5], t1[6], t1[7]);
  } else {
    #pragma unroll
    for (int r = 0; r < 8; ++r) {
      *(float2*)(de_t + (size_t)(j0 + r0 + r) * U_ + u0 + 2 * lane) =
          make_float2(t0[r], t1[r]);
    }
  }
}

// ---------------------------------------------------------------------------
// K2: mu[b,j,i] = sum_u (A + E)*nu / (1 + A*E), A=de_t[j,u], E=Et[b,u,i],
//     then out[b,j,:] = softmax(mu + (mask-1)*1e6).
// 256 blocks (b x 32 j-quads), 512 threads = 8 waves.
// wave w: j = jq (w&3), i-half h (w>>2); lane owns i = h*256 + lane*4 + 0..3.
// No cross-lane ops in the u-loop; A/nu are wave-uniform (scalar path).
// ---------------------------------------------------------------------------
__global__ __launch_bounds__(512) void attn_mu_softmax_kernel(
    const float* __restrict__ Et, const float* __restrict__ de_t,
    const float* __restrict__ nu, const int* __restrict__ mask,
    float* __restrict__ out) {
  __shared__ float red_s[2][4][2];   // [max|sum][jq][h]

  const int tid  = threadIdx.x;
  const int lane = tid & 63;
  const int w    = __builtin_amdgcn_readfirstlane(tid >> 6);  // 0..7, uniform
  const int jq   = w & 3;
  const int h    = w >> 2;
  const int b    = blockIdx.x >> 5;
  const int j    = (blockIdx.x & 31) * 4 + jq;

  const float* __restrict__ Arow  = de_t + (size_t)(b * T_DE_ + j) * U_;
  const float* __restrict__ nuP   = nu;
  const float* __restrict__ Ebase = Et + (size_t)b * U_ * T_EN_ + h * 256 + lane * 4;

  float acc0 = 0.f, acc1 = 0.f, acc2 = 0.f, acc3 = 0.f;

#define LOADC(BUF, U0)                                                   \
  { _Pragma("unroll")                                                    \
    for (int q = 0; q < 8; ++q)                                          \
      BUF[q] = *(const float4*)(Ebase + (size_t)((U0) + q) * T_EN_); }

#define COMP(BUF, U0)                                                    \
  { _Pragma("unroll")                                                    \
    for (int q = 0; q < 8; ++q) {                                        \
      const float A  = Arow[(U0) + q];                                   \
      const float nv = nuP[(U0) + q];                                    \
      const float An = A * nv;                                           \
      acc0 = fmaf(fmaf(nv, BUF[q].x, An),                                \
                  __builtin_amdgcn_rcpf(fmaf(A, BUF[q].x, 1.0f)), acc0); \
      acc1 = fmaf(fmaf(nv, BUF[q].y, An),                                \
                  __builtin_amdgcn_rcpf(fmaf(A, BUF[q].y, 1.0f)), acc1); \
      acc2 = fmaf(fmaf(nv, BUF[q].z, An),                                \
                  __builtin_amdgcn_rcpf(fmaf(A, BUF[q].z, 1.0f)), acc2); \
      acc3 = fmaf(fmaf(nv, BUF[q].w, An),                                \
                  __builtin_amdgcn_rcpf(fmaf(A, BUF[q].w, 1.0f)), acc3); } }

  float4 Ea[8], Eb[8];
  LOADC(Ea, 0)
  for (int u0 = 0; u0 < U_; u0 += 16) {
    LOADC(Eb, u0 + 8)
    COMP(Ea, u0)
    if (u0 + 16 < U_) LOADC(Ea, u0 + 16)
    COMP(Eb, u0 + 8)
  }
#undef LOADC
#undef COMP

  // masked softmax over i (one j per wave; combine the two i-half waves)
  const int4 mk = *(const int4*)(mask + b * T_EN_ + h * 256 + lane * 4);
  float v0 = fmaf((float)mk.x - 1.0f, 1.0e6f, acc0);
  float v1 = fmaf((float)mk.y - 1.0f, 1.0e6f, acc1);
  float v2 = fmaf((float)mk.z - 1.0f, 1.0e6f, acc2);
  float v3 = fmaf((float)mk.w - 1.0f, 1.0e6f, acc3);

  float mx = fmaxf(fmaxf(v0, v1), fmaxf(v2, v3));
  #pragma unroll
  for (int off = 32; off; off >>= 1) mx = fmaxf(mx, __shfl_xor(mx, off, 64));
  if (lane == 0) red_s[0][jq][h] = mx;
  __syncthreads();
  const float M = fmaxf(red_s[0][jq][0], red_s[0][jq][1]);

  const float e0 = __builtin_amdgcn_exp2f((v0 - M) * L2E_);
  const float e1 = __builtin_amdgcn_exp2f((v1 - M) * L2E_);
  const float e2 = __builtin_amdgcn_exp2f((v2 - M) * L2E_);
  const float e3 = __builtin_amdgcn_exp2f((v3 - M) * L2E_);
  float s = (e0 + e1) + (e2 + e3);
  #pragma unroll
  for (int off = 32; off; off >>= 1) s += __shfl_xor(s, off, 64);
  if (lane == 0) red_s[1][jq][h] = s;
  __syncthreads();
  const float S = red_s[1][jq][0] + red_s[1][jq][1];
  const float inv = __builtin_amdgcn_rcpf(S);

  const float4 o = make_float4(e0 * inv, e1 * inv, e2 * inv, e3 * inv);
  *(float4*)(out + (size_t)(b * T_DE_ + j) * T_EN_ + h * 256 + lane * 4) = o;
}

// ---------------------------------------------------------------------------
extern "C" void kernel_launch(void* const* d_in, const int* in_sizes, int n_in,
                              void* d_out, int out_size, void* d_ws, size_t ws_size,
                              hipStream_t stream) {
  const float* en   = (const float*)d_in[0];   // [B, T_EN, D]
  const float* de   = (const float*)d_in[1];   // [B, T_DE, D]
  const int*   mask = (const int*)d_in[2];     // [B, T_EN]
  const float* w_en = (const float*)d_in[3];   // [D, U]
  const float* w_de = (const float*)d_in[4];   // [D, U]
  const float* nu   = (const float*)d_in[5];   // [U, 1]
  float* out = (float*)d_out;                  // [B, T_DE, T_EN]

  float* Et   = (float*)d_ws;                          // tanh(en@w_en)^T: [B][U][T_EN], 4 MB
  float* de_t = Et + (size_t)B_ * U_ * T_EN_;          // tanh(de@w_de):   [B*T_DE][U], 1 MB

  proj_tanh_kernel<<<dim3(320), 256, 0, stream>>>(en, de, w_en, w_de, Et, de_t);
  attn_mu_softmax_kernel<<<dim3(B_ * (T_DE_ / 4)), 512, 0, stream>>>(Et, de_t, nu, mask, out);
}

// Round 5
// 65.527 us; speedup vs baseline: 1.2376x; 1.0981x over previous
//
#include <hip/hip_runtime.h>
#include <cstddef>
#include <cstdint>

#define B_    8
#define T_EN_ 512
#define T_DE_ 128
#define D_    512
#define U_    256

// tanh(x) = 1 - 2/(exp2(C*x)+1), C = 2*log2(e)
#define TANH_C 2.8853900817779268f
#define L2E_   1.4426950408889634f
#define TANH_CLAMP 0.99999994f

typedef float f32x4 __attribute__((ext_vector_type(4)));
typedef short s16x8 __attribute__((ext_vector_type(8)));

__device__ __forceinline__ float fast_tanh_clamped(float x) {
  const float e = __builtin_amdgcn_exp2f(x * TANH_C);
  float t = fmaf(-2.0f, __builtin_amdgcn_rcpf(e + 1.0f), 1.0f);
  return fminf(fmaxf(t, -TANH_CLAMP), TANH_CLAMP);
}

// split f32 -> bf16 hi (truncated) + bf16 lo (truncated remainder)
__device__ __forceinline__ void split_bf16(float x, short& hi, short& lo) {
  const unsigned u = __float_as_uint(x);
  hi = (short)(u >> 16);
  const float hf = __uint_as_float(u & 0xffff0000u);
  const float lf = x - hf;
  lo = (short)(__float_as_uint(lf) >> 16);
}

// ---------------------------------------------------------------------------
// Prepack: convert en/de/w_en/w_de to bf16 hi/lo planes in MFMA fragment order.
// Fragment unit = 8 bf16 for lane (g = lane>>4, n = lane&15):
//   k-offset within 32-k step: kmap(g,e) = g*4 + (e&3) + 16*(e>>2)
// Row-side (en/de; operand indexed by its ROW = m or n = lane&15):
//   en unit idx:  (((b*16 + s)*32 + t)*4 + g)*16 + n      (t = i>>4, n = i&15)
//   de unit idx:  ((s*64 + t64)*4 + g)*16 + n             (t64 = row>>4)
// w-side (operand indexed by u = lane&15):
//   w  unit idx:  ((s*16 + US)*4 + g)*16 + n              (u = US*16 + n)
// grid 1408 x 256: [0,1024) en rows, [1024,1280) de rows, [1280,1344) w_en,
// [1344,1408) w_de. One unit per thread.
// ---------------------------------------------------------------------------
__global__ __launch_bounds__(256) void prepack_kernel(
    const float* __restrict__ en, const float* __restrict__ de,
    const float* __restrict__ w_en, const float* __restrict__ w_de,
    short* __restrict__ en_hi, short* __restrict__ en_lo,
    short* __restrict__ de_hi, short* __restrict__ de_lo,
    short* __restrict__ wen_hi, short* __restrict__ wen_lo,
    short* __restrict__ wde_hi, short* __restrict__ wde_lo) {
  const int blk = blockIdx.x;
  const int tid = threadIdx.x;
  float v[8];
  short* ph;
  short* pl;
  size_t ub;

  if (blk < 1280) {
    // row units (en / de)
    const int gu = blk * 256 + tid;
    const int n = gu & 15;
    const int g = (gu >> 4) & 3;
    const int s = (gu >> 6) & 15;
    const int rb = gu >> 10;             // 0..319 row-blocks of 16 rows
    const float* src;
    if (rb < 256) {                      // en: b = rb>>5, t = rb&31
      const int b = rb >> 5, t = rb & 31;
      src = en + ((size_t)rb * 16 + n) * D_;
      ub = ((size_t)((b * 16 + s) * 32 + t) * 4 + g) * 16 + n;
      ph = en_hi; pl = en_lo;
    } else {                             // de: t64 = rb-256
      const int t64 = rb - 256;
      src = de + ((size_t)t64 * 16 + n) * D_;
      ub = ((size_t)(s * 64 + t64) * 4 + g) * 16 + n;
      ph = de_hi; pl = de_lo;
    }
    const int kb = s * 32 + g * 4;
    const float4 fa = *(const float4*)(src + kb);
    const float4 fb = *(const float4*)(src + kb + 16);
    v[0] = fa.x; v[1] = fa.y; v[2] = fa.z; v[3] = fa.w;
    v[4] = fb.x; v[5] = fb.y; v[6] = fb.z; v[7] = fb.w;
  } else {
    // w units
    const int wb = blk - 1280;           // 0..127
    const bool is_en = wb < 64;
    const int wq = wb & 63;
    const int s = wq >> 2, USq = wq & 3;
    const int n = tid & 15;
    const int g = (tid >> 4) & 3;
    const int US = USq * 4 + (tid >> 6);
    const float* W = is_en ? w_en : w_de;
    ph = is_en ? wen_hi : wde_hi;
    pl = is_en ? wen_lo : wde_lo;
    #pragma unroll
    for (int e = 0; e < 8; ++e) {
      const int k = s * 32 + g * 4 + (e & 3) + 16 * (e >> 2);
      v[e] = W[(size_t)k * U_ + US * 16 + n];
    }
    ub = ((size_t)(s * 16 + US) * 4 + g) * 16 + n;
  }

  s16x8 h8, l8;
  #pragma unroll
  for (int e = 0; e < 8; ++e) {
    short h, l;
    split_bf16(v[e], h, l);
    h8[e] = h; l8[e] = l;
  }
  *(s16x8*)(ph + ub * 8) = h8;
  *(s16x8*)(pl + ub * 8) = l8;
}

// ---------------------------------------------------------------------------
// K1: MFMA projections + tanh (split-bf16: hi*hi + hi*lo + lo*hi).
// blocks [0,128): en-branch, block (b = blk>>4, it = blk&15): D[u][i],
//   wave wv: u-range wv*64, i-tile it*32 (2 subtiles). -> Et[b][u][i]
// blocks [128,160): de-branch, block jt: D[j][u], wave wv: u-range wv*64,
//   j-tile jt*32 (2 subtiles). -> de_t[j][u]
// C/D layout (verified): col = lane&15, row = (lane>>4)*4 + reg.
// ---------------------------------------------------------------------------
__global__ __launch_bounds__(256) void mfma_proj_kernel(
    const short* __restrict__ en_hi, const short* __restrict__ en_lo,
    const short* __restrict__ de_hi, const short* __restrict__ de_lo,
    const short* __restrict__ wen_hi, const short* __restrict__ wen_lo,
    const short* __restrict__ wde_hi, const short* __restrict__ wde_lo,
    float* __restrict__ Et, float* __restrict__ de_t) {
  const int blk = blockIdx.x;
  const int tid = threadIdx.x;
  const int lane = tid & 63;
  const int wv = tid >> 6;            // 0..3
  const int rl = lane >> 4, cl = lane & 15;

  f32x4 acc[8] = {};

  if (blk < 128) {
    const int b = blk >> 4, it = blk & 15;
    #pragma unroll 2
    for (int s = 0; s < 16; ++s) {
      s16x8 ah[4], al[4], bh[2], bl[2];
      #pragma unroll
      for (int us = 0; us < 4; ++us) {
        const size_t off = ((size_t)(s * 16 + wv * 4 + us) * 64 + lane) * 8;
        ah[us] = *(const s16x8*)(wen_hi + off);
        al[us] = *(const s16x8*)(wen_lo + off);
      }
      #pragma unroll
      for (int is = 0; is < 2; ++is) {
        const size_t off = ((size_t)((b * 16 + s) * 32 + it * 2 + is) * 64 + lane) * 8;
        bh[is] = *(const s16x8*)(en_hi + off);
        bl[is] = *(const s16x8*)(en_lo + off);
      }
      #pragma unroll
      for (int us = 0; us < 4; ++us)
        #pragma unroll
        for (int is = 0; is < 2; ++is) {
          const int x = us * 2 + is;
          acc[x] = __builtin_amdgcn_mfma_f32_16x16x32_bf16(ah[us], bh[is], acc[x], 0, 0, 0);
          acc[x] = __builtin_amdgcn_mfma_f32_16x16x32_bf16(ah[us], bl[is], acc[x], 0, 0, 0);
          acc[x] = __builtin_amdgcn_mfma_f32_16x16x32_bf16(al[us], bh[is], acc[x], 0, 0, 0);
        }
    }
    #pragma unroll
    for (int us = 0; us < 4; ++us)
      #pragma unroll
      for (int is = 0; is < 2; ++is) {
        const f32x4 a = acc[us * 2 + is];
        #pragma unroll
        for (int r = 0; r < 4; ++r) {
          const int u = wv * 64 + us * 16 + rl * 4 + r;
          const int i = it * 32 + is * 16 + cl;
          Et[((size_t)b * U_ + u) * T_EN_ + i] = fast_tanh_clamped(a[r]);
        }
      }
  } else {
    const int jt = blk - 128;           // 0..31
    #pragma unroll 2
    for (int s = 0; s < 16; ++s) {
      s16x8 ah[2], al[2], bh[4], bl[4];
      #pragma unroll
      for (int ms = 0; ms < 2; ++ms) {
        const size_t off = ((size_t)(s * 64 + jt * 2 + ms) * 64 + lane) * 8;
        ah[ms] = *(const s16x8*)(de_hi + off);
        al[ms] = *(const s16x8*)(de_lo + off);
      }
      #pragma unroll
      for (int us = 0; us < 4; ++us) {
        const size_t off = ((size_t)(s * 16 + wv * 4 + us) * 64 + lane) * 8;
        bh[us] = *(const s16x8*)(wde_hi + off);
        bl[us] = *(const s16x8*)(wde_lo + off);
      }
      #pragma unroll
      for (int ms = 0; ms < 2; ++ms)
        #pragma unroll
        for (int us = 0; us < 4; ++us) {
          const int x = ms * 4 + us;
          acc[x] = __builtin_amdgcn_mfma_f32_16x16x32_bf16(ah[ms], bh[us], acc[x], 0, 0, 0);
          acc[x] = __builtin_amdgcn_mfma_f32_16x16x32_bf16(ah[ms], bl[us], acc[x], 0, 0, 0);
          acc[x] = __builtin_amdgcn_mfma_f32_16x16x32_bf16(al[ms], bh[us], acc[x], 0, 0, 0);
        }
    }
    #pragma unroll
    for (int ms = 0; ms < 2; ++ms)
      #pragma unroll
      for (int us = 0; us < 4; ++us) {
        const f32x4 a = acc[ms * 4 + us];
        #pragma unroll
        for (int r = 0; r < 4; ++r) {
          const int j = jt * 32 + ms * 16 + rl * 4 + r;   // flat de row
          const int u = wv * 64 + us * 16 + cl;
          de_t[(size_t)j * U_ + u] = fast_tanh_clamped(a[r]);
        }
      }
  }
}

// ---------------------------------------------------------------------------
// Fallback K1 (round-4, verified): used only if ws_size < 16 MB.
// ---------------------------------------------------------------------------
__global__ __launch_bounds__(256) void proj_tanh_fallback(
    const float* __restrict__ en, const float* __restrict__ de,
    const float* __restrict__ w_en, const float* __restrict__ w_de,
    float* __restrict__ Et, float* __restrict__ de_t) {
  __shared__ float xs[16 * D_];
  const int tid = threadIdx.x;
  const int bx = blockIdx.x;
  const bool enb = bx < 256;
  const float *X, *W;
  int b = 0, i0 = 0, j0 = 0;
  if (enb) {
    b = bx >> 5; i0 = (bx & 31) * 16;
    X = en + ((size_t)b * T_EN_ + i0) * D_;
    W = w_en;
  } else {
    j0 = (bx - 256) * 16;
    X = de + (size_t)j0 * D_;
    W = w_de;
  }
  {
    const float4* Xv = (const float4*)X;
    float4* Sv = (float4*)xs;
    #pragma unroll
    for (int q = 0; q < 8; ++q) Sv[tid + 256 * q] = Xv[tid + 256 * q];
  }
  __syncthreads();
  const int lane = tid & 63;
  const int wv = __builtin_amdgcn_readfirstlane(tid >> 6);
  const int u0 = (wv & 1) * 128;
  const int r0 = (wv >> 1) * 8;
  const float* wp = W + u0 + 2 * lane;
  float2 wc[8], wn[8];
  #pragma unroll
  for (int q = 0; q < 8; ++q) wc[q] = *(const float2*)(wp + (size_t)q * U_);
  float a0[8] = {}, a1[8] = {};
  for (int d0 = 0; d0 < D_; d0 += 8) {
    if (d0 + 8 < D_) {
      #pragma unroll
      for (int q = 0; q < 8; ++q)
        wn[q] = *(const float2*)(wp + (size_t)(d0 + 8 + q) * U_);
    }
    #pragma unroll
    for (int r = 0; r < 8; ++r) {
      const float4 xa = *(const float4*)(xs + (r0 + r) * D_ + d0);
      const float4 xb = *(const float4*)(xs + (r0 + r) * D_ + d0 + 4);
      a0[r] = fmaf(xa.x, wc[0].x, a0[r]);  a1[r] = fmaf(xa.x, wc[0].y, a1[r]);
      a0[r] = fmaf(xa.y, wc[1].x, a0[r]);  a1[r] = fmaf(xa.y, wc[1].y, a1[r]);
      a0[r] = fmaf(xa.z, wc[2].x, a0[r]);  a1[r] = fmaf(xa.z, wc[2].y, a1[r]);
      a0[r] = fmaf(xa.w, wc[3].x, a0[r]);  a1[r] = fmaf(xa.w, wc[3].y, a1[r]);
      a0[r] = fmaf(xb.x, wc[4].x, a0[r]);  a1[r] = fmaf(xb.x, wc[4].y, a1[r]);
      a0[r] = fmaf(xb.y, wc[5].x, a0[r]);  a1[r] = fmaf(xb.y, wc[5].y, a1[r]);
      a0[r] = fmaf(xb.z, wc[6].x, a0[r]);  a1[r] = fmaf(xb.z, wc[6].y, a1[r]);
      a0[r] = fmaf(xb.w, wc[7].x, a0[r]);  a1[r] = fmaf(xb.w, wc[7].y, a1[r]);
    }
    #pragma unroll
    for (int q = 0; q < 8; ++q) wc[q] = wn[q];
  }
  float t0[8], t1[8];
  #pragma unroll
  for (int r = 0; r < 8; ++r) {
    t0[r] = fast_tanh_clamped(a0[r]);
    t1[r] = fast_tanh_clamped(a1[r]);
  }
  if (enb) {
    const int uA = u0 + 2 * lane;
    float* pA = Et + ((size_t)b * U_ + uA) * T_EN_ + i0 + r0;
    float* pB = pA + T_EN_;
    *(float4*)(pA + 0) = make_float4(t0[0], t0[1], t0[2], t0[3]);
    *(float4*)(pA + 4) = make_float4(t0[4], t0[5], t0[6], t0[7]);
    *(float4*)(pB + 0) = make_float4(t1[0], t1[1], t1[2], t1[3]);
    *(float4*)(pB + 4) = make_float4(t1[4], t1[5], t1[6], t1[7]);
  } else {
    #pragma unroll
    for (int r = 0; r < 8; ++r)
      *(float2*)(de_t + (size_t)(j0 + r0 + r) * U_ + u0 + 2 * lane) =
          make_float2(t0[r], t1[r]);
  }
}

// ---------------------------------------------------------------------------
// K2: mu = sum_u (A+E)*nu/(1+A*E); softmax with mask.
// grid 256 = jg*8 + b (pins each b to one XCD for Et L2 residency), 512 thr.
// wave w: q = w&3 (i-quarter, lane holds 2 i), jp = w>>2 (j-pair of the 4 j).
// Each E value reused for 2 j -> Et read 2x per block (128 MB total).
// ---------------------------------------------------------------------------
__global__ __launch_bounds__(512) void attn_mu_softmax_kernel(
    const float* __restrict__ Et, const float* __restrict__ de_t,
    const float* __restrict__ nu, const int* __restrict__ mask,
    float* __restrict__ out) {
  __shared__ float mu_s[4][T_EN_];

  const int tid  = threadIdx.x;
  const int lane = tid & 63;
  const int w    = __builtin_amdgcn_readfirstlane(tid >> 6);  // 0..7
  const int q    = w & 3;
  const int jp   = w >> 2;
  const int b    = blockIdx.x & 7;
  const int jg   = blockIdx.x >> 3;    // 0..31

  const float* __restrict__ Eb  = Et + (size_t)b * U_ * T_EN_ + q * 128 + lane * 2;
  const float* __restrict__ A0p = de_t + (size_t)(b * T_DE_ + jg * 4 + jp * 2) * U_;
  const float* __restrict__ A1p = A0p + U_;

  float ac00 = 0.f, ac01 = 0.f, ac10 = 0.f, ac11 = 0.f;  // [jl][il]

  float2 Ea[8], Ebf[8];
  #pragma unroll
  for (int c = 0; c < 8; ++c) Ea[c] = *(const float2*)(Eb + (size_t)c * T_EN_);

#define K2_COMP(BUF, U0)                                                  \
  { _Pragma("unroll")                                                     \
    for (int c = 0; c < 8; ++c) {                                         \
      const int u = (U0) + c;                                             \
      const float A0 = A0p[u], A1 = A1p[u], nv = nu[u];                   \
      const float An0 = A0 * nv, An1 = A1 * nv;                           \
      const float ex = BUF[c].x, ey = BUF[c].y;                           \
      ac00 = fmaf(fmaf(nv, ex, An0),                                      \
                  __builtin_amdgcn_rcpf(fmaf(A0, ex, 1.0f)), ac00);       \
      ac01 = fmaf(fmaf(nv, ey, An0),                                      \
                  __builtin_amdgcn_rcpf(fmaf(A0, ey, 1.0f)), ac01);       \
      ac10 = fmaf(fmaf(nv, ex, An1),                                      \
                  __builtin_amdgcn_rcpf(fmaf(A1, ex, 1.0f)), ac10);       \
      ac11 = fmaf(fmaf(nv, ey, An1),                                      \
                  __builtin_amdgcn_rcpf(fmaf(A1, ey, 1.0f)), ac11); } }

  for (int u0 = 0; u0 < U_; u0 += 16) {
    #pragma unroll
    for (int c = 0; c < 8; ++c)
      Ebf[c] = *(const float2*)(Eb + (size_t)(u0 + 8 + c) * T_EN_);
    K2_COMP(Ea, u0)
    if (u0 + 16 < U_) {
      #pragma unroll
      for (int c = 0; c < 8; ++c)
        Ea[c] = *(const float2*)(Eb + (size_t)(u0 + 16 + c) * T_EN_);
    }
    K2_COMP(Ebf, u0 + 8)
  }
#undef K2_COMP

  *(float2*)&mu_s[jp * 2 + 0][q * 128 + lane * 2] = make_float2(ac00, ac01);
  *(float2*)&mu_s[jp * 2 + 1][q * 128 + lane * 2] = make_float2(ac10, ac11);
  __syncthreads();

  if (w < 4) {
    const int jj = jg * 4 + w;
    float vals[8];
    float mx = -3.0e38f;
    #pragma unroll
    for (int k = 0; k < 8; ++k) {
      const int i = lane + 64 * k;
      const float mi = (float)mask[b * T_EN_ + i];
      const float v = fmaf(mi - 1.0f, 1.0e6f, mu_s[w][i]);
      vals[k] = v;
      mx = fmaxf(mx, v);
    }
    #pragma unroll
    for (int off = 32; off; off >>= 1) mx = fmaxf(mx, __shfl_xor(mx, off, 64));
    float sum = 0.0f;
    #pragma unroll
    for (int k = 0; k < 8; ++k) {
      const float e = __builtin_amdgcn_exp2f((vals[k] - mx) * L2E_);
      vals[k] = e;
      sum += e;
    }
    #pragma unroll
    for (int off = 32; off; off >>= 1) sum += __shfl_xor(sum, off, 64);
    const float inv = __builtin_amdgcn_rcpf(sum);
    float* op = out + (size_t)(b * T_DE_ + jj) * T_EN_;
    #pragma unroll
    for (int k = 0; k < 8; ++k) op[lane + 64 * k] = vals[k] * inv;
  }
}

// ---------------------------------------------------------------------------
extern "C" void kernel_launch(void* const* d_in, const int* in_sizes, int n_in,
                              void* d_out, int out_size, void* d_ws, size_t ws_size,
                              hipStream_t stream) {
  const float* en   = (const float*)d_in[0];   // [B, T_EN, D]
  const float* de   = (const float*)d_in[1];   // [B, T_DE, D]
  const int*   mask = (const int*)d_in[2];     // [B, T_EN]
  const float* w_en = (const float*)d_in[3];   // [D, U]
  const float* w_de = (const float*)d_in[4];   // [D, U]
  const float* nu   = (const float*)d_in[5];   // [U, 1]
  float* out = (float*)d_out;                  // [B, T_DE, T_EN]

  // ws layout
  float* Et   = (float*)d_ws;                  // [B][U][T_EN]  4 MB
  float* de_t = Et + (size_t)B_ * U_ * T_EN_;  // [B*T_DE][U]   1 MB
  short* p    = (short*)(de_t + (size_t)B_ * T_DE_ * U_);
  short* en_hi = p;                 p += 2097152;   // B*T_EN*D
  short* en_lo = p;                 p += 2097152;
  short* de_hi = p;                 p += 524288;    // B*T_DE*D
  short* de_lo = p;                 p += 524288;
  short* wen_hi = p;                p += 131072;    // D*U
  short* wen_lo = p;                p += 131072;
  short* wde_hi = p;                p += 131072;
  short* wde_lo = p;                p += 131072;
  const size_t need = (size_t)(1048576 + 262144) * 4 +
                      (size_t)(2 * 2097152 + 2 * 524288 + 4 * 131072) * 2;  // 16 MB

  if (ws_size >= need) {
    prepack_kernel<<<dim3(1408), 256, 0, stream>>>(
        en, de, w_en, w_de, en_hi, en_lo, de_hi, de_lo,
        wen_hi, wen_lo, wde_hi, wde_lo);
    mfma_proj_kernel<<<dim3(160), 256, 0, stream>>>(
        en_hi, en_lo, de_hi, de_lo, wen_hi, wen_lo, wde_hi, wde_lo, Et, de_t);
  } else {
    proj_tanh_fallback<<<dim3(320), 256, 0, stream>>>(en, de, w_en, w_de, Et, de_t);
  }
  attn_mu_softmax_kernel<<<dim3(256), 512, 0, stream>>>(Et, de_t, nu, mask, out);
}

// Round 6
// 50.670 us; speedup vs baseline: 1.6005x; 1.2932x over previous
//
#include <hip/hip_runtime.h>
#include <cstddef>
#include <cstdint>

#define B_    8
#define T_EN_ 512
#define T_DE_ 128
#define D_    512
#define U_    256

// tanh(x) = 1 - 2/(exp2(C*x)+1), C = 2*log2(e)
#define TANH_C 2.8853900817779268f
#define L2E_   1.4426950408889634f
#define TANH_CLAMP 0.99999994f

typedef float f32x4 __attribute__((ext_vector_type(4)));
typedef short s16x8 __attribute__((ext_vector_type(8)));

__device__ __forceinline__ float fast_tanh_clamped(float x) {
  const float e = __builtin_amdgcn_exp2f(x * TANH_C);
  float t = fmaf(-2.0f, __builtin_amdgcn_rcpf(e + 1.0f), 1.0f);
  return fminf(fmaxf(t, -TANH_CLAMP), TANH_CLAMP);
}

// split f32 -> bf16 hi (truncated) + bf16 lo (truncated remainder)
__device__ __forceinline__ void split_bf16(float x, short& hi, short& lo) {
  const unsigned u = __float_as_uint(x);
  hi = (short)(u >> 16);
  const float hf = __uint_as_float(u & 0xffff0000u);
  const float lf = x - hf;
  lo = (short)(__float_as_uint(lf) >> 16);
}

// ---------------------------------------------------------------------------
// Prepack (unchanged from round 5, verified): bf16 hi/lo fragment planes.
// unit idx formulas give frag byte offset = unit*16; lane = g*16+n.
// ---------------------------------------------------------------------------
__global__ __launch_bounds__(256) void prepack_kernel(
    const float* __restrict__ en, const float* __restrict__ de,
    const float* __restrict__ w_en, const float* __restrict__ w_de,
    short* __restrict__ en_hi, short* __restrict__ en_lo,
    short* __restrict__ de_hi, short* __restrict__ de_lo,
    short* __restrict__ wen_hi, short* __restrict__ wen_lo,
    short* __restrict__ wde_hi, short* __restrict__ wde_lo) {
  const int blk = blockIdx.x;
  const int tid = threadIdx.x;
  float v[8];
  short* ph;
  short* pl;
  size_t ub;

  if (blk < 1280) {
    const int gu = blk * 256 + tid;
    const int n = gu & 15;
    const int g = (gu >> 4) & 3;
    const int s = (gu >> 6) & 15;
    const int rb = gu >> 10;
    const float* src;
    if (rb < 256) {
      const int b = rb >> 5, t = rb & 31;
      src = en + ((size_t)rb * 16 + n) * D_;
      ub = ((size_t)((b * 16 + s) * 32 + t) * 4 + g) * 16 + n;
      ph = en_hi; pl = en_lo;
    } else {
      const int t64 = rb - 256;
      src = de + ((size_t)t64 * 16 + n) * D_;
      ub = ((size_t)(s * 64 + t64) * 4 + g) * 16 + n;
      ph = de_hi; pl = de_lo;
    }
    const int kb = s * 32 + g * 4;
    const float4 fa = *(const float4*)(src + kb);
    const float4 fb = *(const float4*)(src + kb + 16);
    v[0] = fa.x; v[1] = fa.y; v[2] = fa.z; v[3] = fa.w;
    v[4] = fb.x; v[5] = fb.y; v[6] = fb.z; v[7] = fb.w;
  } else {
    const int wb = blk - 1280;
    const bool is_en = wb < 64;
    const int wq = wb & 63;
    const int s = wq >> 2, USq = wq & 3;
    const int n = tid & 15;
    const int g = (tid >> 4) & 3;
    const int US = USq * 4 + (tid >> 6);
    const float* W = is_en ? w_en : w_de;
    ph = is_en ? wen_hi : wde_hi;
    pl = is_en ? wen_lo : wde_lo;
    #pragma unroll
    for (int e = 0; e < 8; ++e) {
      const int k = s * 32 + g * 4 + (e & 3) + 16 * (e >> 2);
      v[e] = W[(size_t)k * U_ + US * 16 + n];
    }
    ub = ((size_t)(s * 16 + US) * 4 + g) * 16 + n;
  }

  s16x8 h8, l8;
  #pragma unroll
  for (int e = 0; e < 8; ++e) {
    short h, l;
    split_bf16(v[e], h, l);
    h8[e] = h; l8[e] = l;
  }
  *(s16x8*)(ph + ub * 8) = h8;
  *(s16x8*)(pl + ub * 8) = l8;
}

// ---------------------------------------------------------------------------
// K1: MFMA projections + tanh. 640 blocks x 256 thr (2.5 waves/SIMD).
//  en blocks [0,512): (b, uh, it): 128u x 16i tile; wave = 32u x 16i (2 acc).
//  de blocks [512,640): (t64, uh): 16j x 128u tile; wave = 16j x 32u (2 acc).
// Explicit 2-stage frag prefetch (load step s+1 while MFMA step s).
// C/D layout (HW-verified in r5): col = lane&15, row = (lane>>4)*4 + reg.
// ---------------------------------------------------------------------------
__global__ __launch_bounds__(256) void mfma_proj_kernel(
    const short* __restrict__ en_hi, const short* __restrict__ en_lo,
    const short* __restrict__ de_hi, const short* __restrict__ de_lo,
    const short* __restrict__ wen_hi, const short* __restrict__ wen_lo,
    const short* __restrict__ wde_hi, const short* __restrict__ wde_lo,
    float* __restrict__ Et, float* __restrict__ de_t) {
  const int blk = blockIdx.x;
  const int tid = threadIdx.x;
  const int lane = tid & 63;
  const int wv = tid >> 6;
  const int rl = lane >> 4, cl = lane & 15;

  f32x4 acc[2] = {};
  s16x8 bufA[6], bufB[6];

  if (blk < 512) {
    const int b  = blk >> 6;
    const int uh = (blk >> 5) & 1;
    const int it = blk & 31;
    const int US0 = uh * 8 + wv * 2;

#define LOAD_EN(DST, S)                                                   \
    { const size_t oa0 = ((size_t)((S) * 16 + US0) * 64 + lane) * 8;      \
      const size_t ob  = ((size_t)((b * 16 + (S)) * 32 + it) * 64 + lane) * 8; \
      DST[0] = *(const s16x8*)(wen_hi + oa0);                             \
      DST[1] = *(const s16x8*)(wen_lo + oa0);                             \
      DST[2] = *(const s16x8*)(wen_hi + oa0 + 512);                       \
      DST[3] = *(const s16x8*)(wen_lo + oa0 + 512);                       \
      DST[4] = *(const s16x8*)(en_hi + ob);                               \
      DST[5] = *(const s16x8*)(en_lo + ob); }
#define MFMA_EN(S)                                                        \
    { acc[0] = __builtin_amdgcn_mfma_f32_16x16x32_bf16(S[0], S[4], acc[0], 0, 0, 0); \
      acc[0] = __builtin_amdgcn_mfma_f32_16x16x32_bf16(S[0], S[5], acc[0], 0, 0, 0); \
      acc[0] = __builtin_amdgcn_mfma_f32_16x16x32_bf16(S[1], S[4], acc[0], 0, 0, 0); \
      acc[1] = __builtin_amdgcn_mfma_f32_16x16x32_bf16(S[2], S[4], acc[1], 0, 0, 0); \
      acc[1] = __builtin_amdgcn_mfma_f32_16x16x32_bf16(S[2], S[5], acc[1], 0, 0, 0); \
      acc[1] = __builtin_amdgcn_mfma_f32_16x16x32_bf16(S[3], S[4], acc[1], 0, 0, 0); }

    LOAD_EN(bufA, 0)
    for (int s = 0; s < 16; s += 2) {
      LOAD_EN(bufB, s + 1)
      MFMA_EN(bufA)
      if (s + 2 < 16) LOAD_EN(bufA, s + 2)
      MFMA_EN(bufB)
    }
#undef LOAD_EN
#undef MFMA_EN

    #pragma unroll
    for (int us = 0; us < 2; ++us) {
      #pragma unroll
      for (int r = 0; r < 4; ++r) {
        const int u = (US0 + us) * 16 + rl * 4 + r;
        const int i = it * 16 + cl;
        Et[((size_t)b * U_ + u) * T_EN_ + i] = fast_tanh_clamped(acc[us][r]);
      }
    }
  } else {
    const int y = blk - 512;
    const int t64 = y >> 1;
    const int uh = y & 1;
    const int US0 = uh * 8 + wv * 2;

#define LOAD_DE(DST, S)                                                   \
    { const size_t oa = ((size_t)((S) * 64 + t64) * 64 + lane) * 8;       \
      const size_t ob = ((size_t)((S) * 16 + US0) * 64 + lane) * 8;       \
      DST[0] = *(const s16x8*)(de_hi + oa);                               \
      DST[1] = *(const s16x8*)(de_lo + oa);                               \
      DST[2] = *(const s16x8*)(wde_hi + ob);                              \
      DST[3] = *(const s16x8*)(wde_lo + ob);                              \
      DST[4] = *(const s16x8*)(wde_hi + ob + 512);                        \
      DST[5] = *(const s16x8*)(wde_lo + ob + 512); }
#define MFMA_DE(S)                                                        \
    { acc[0] = __builtin_amdgcn_mfma_f32_16x16x32_bf16(S[0], S[2], acc[0], 0, 0, 0); \
      acc[0] = __builtin_amdgcn_mfma_f32_16x16x32_bf16(S[0], S[3], acc[0], 0, 0, 0); \
      acc[0] = __builtin_amdgcn_mfma_f32_16x16x32_bf16(S[1], S[2], acc[0], 0, 0, 0); \
      acc[1] = __builtin_amdgcn_mfma_f32_16x16x32_bf16(S[0], S[4], acc[1], 0, 0, 0); \
      acc[1] = __builtin_amdgcn_mfma_f32_16x16x32_bf16(S[0], S[5], acc[1], 0, 0, 0); \
      acc[1] = __builtin_amdgcn_mfma_f32_16x16x32_bf16(S[1], S[4], acc[1], 0, 0, 0); }

    LOAD_DE(bufA, 0)
    for (int s = 0; s < 16; s += 2) {
      LOAD_DE(bufB, s + 1)
      MFMA_DE(bufA)
      if (s + 2 < 16) LOAD_DE(bufA, s + 2)
      MFMA_DE(bufB)
    }
#undef LOAD_DE
#undef MFMA_DE

    #pragma unroll
    for (int us = 0; us < 2; ++us) {
      #pragma unroll
      for (int r = 0; r < 4; ++r) {
        const int j = t64 * 16 + rl * 4 + r;
        const int u = (US0 + us) * 16 + cl;
        de_t[(size_t)j * U_ + u] = fast_tanh_clamped(acc[us][r]);
      }
    }
  }
}

// ---------------------------------------------------------------------------
// Fallback K1 (verified round-4 path): used only if ws_size < 16 MB.
// ---------------------------------------------------------------------------
__global__ __launch_bounds__(256) void proj_tanh_fallback(
    const float* __restrict__ en, const float* __restrict__ de,
    const float* __restrict__ w_en, const float* __restrict__ w_de,
    float* __restrict__ Et, float* __restrict__ de_t) {
  __shared__ float xs[16 * D_];
  const int tid = threadIdx.x;
  const int bx = blockIdx.x;
  const bool enb = bx < 256;
  const float *X, *W;
  int b = 0, i0 = 0, j0 = 0;
  if (enb) {
    b = bx >> 5; i0 = (bx & 31) * 16;
    X = en + ((size_t)b * T_EN_ + i0) * D_;
    W = w_en;
  } else {
    j0 = (bx - 256) * 16;
    X = de + (size_t)j0 * D_;
    W = w_de;
  }
  {
    const float4* Xv = (const float4*)X;
    float4* Sv = (float4*)xs;
    #pragma unroll
    for (int q = 0; q < 8; ++q) Sv[tid + 256 * q] = Xv[tid + 256 * q];
  }
  __syncthreads();
  const int lane = tid & 63;
  const int wv = __builtin_amdgcn_readfirstlane(tid >> 6);
  const int u0 = (wv & 1) * 128;
  const int r0 = (wv >> 1) * 8;
  const float* wp = W + u0 + 2 * lane;
  float2 wc[8], wn[8];
  #pragma unroll
  for (int q = 0; q < 8; ++q) wc[q] = *(const float2*)(wp + (size_t)q * U_);
  float a0[8] = {}, a1[8] = {};
  for (int d0 = 0; d0 < D_; d0 += 8) {
    if (d0 + 8 < D_) {
      #pragma unroll
      for (int q = 0; q < 8; ++q)
        wn[q] = *(const float2*)(wp + (size_t)(d0 + 8 + q) * U_);
    }
    #pragma unroll
    for (int r = 0; r < 8; ++r) {
      const float4 xa = *(const float4*)(xs + (r0 + r) * D_ + d0);
      const float4 xb = *(const float4*)(xs + (r0 + r) * D_ + d0 + 4);
      a0[r] = fmaf(xa.x, wc[0].x, a0[r]);  a1[r] = fmaf(xa.x, wc[0].y, a1[r]);
      a0[r] = fmaf(xa.y, wc[1].x, a0[r]);  a1[r] = fmaf(xa.y, wc[1].y, a1[r]);
      a0[r] = fmaf(xa.z, wc[2].x, a0[r]);  a1[r] = fmaf(xa.z, wc[2].y, a1[r]);
      a0[r] = fmaf(xa.w, wc[3].x, a0[r]);  a1[r] = fmaf(xa.w, wc[3].y, a1[r]);
      a0[r] = fmaf(xb.x, wc[4].x, a0[r]);  a1[r] = fmaf(xb.x, wc[4].y, a1[r]);
      a0[r] = fmaf(xb.y, wc[5].x, a0[r]);  a1[r] = fmaf(xb.y, wc[5].y, a1[r]);
      a0[r] = fmaf(xb.z, wc[6].x, a0[r]);  a1[r] = fmaf(xb.z, wc[6].y, a1[r]);
      a0[r] = fmaf(xb.w, wc[7].x, a0[r]);  a1[r] = fmaf(xb.w, wc[7].y, a1[r]);
    }
    #pragma unroll
    for (int q = 0; q < 8; ++q) wc[q] = wn[q];
  }
  float t0[8], t1[8];
  #pragma unroll
  for (int r = 0; r < 8; ++r) {
    t0[r] = fast_tanh_clamped(a0[r]);
    t1[r] = fast_tanh_clamped(a1[r]);
  }
  if (enb) {
    const int uA = u0 + 2 * lane;
    float* pA = Et + ((size_t)b * U_ + uA) * T_EN_ + i0 + r0;
    float* pB = pA + T_EN_;
    *(float4*)(pA + 0) = make_float4(t0[0], t0[1], t0[2], t0[3]);
    *(float4*)(pA + 4) = make_float4(t0[4], t0[5], t0[6], t0[7]);
    *(float4*)(pB + 0) = make_float4(t1[0], t1[1], t1[2], t1[3]);
    *(float4*)(pB + 4) = make_float4(t1[4], t1[5], t1[6], t1[7]);
  } else {
    #pragma unroll
    for (int r = 0; r < 8; ++r)
      *(float2*)(de_t + (size_t)(j0 + r0 + r) * U_ + u0 + 2 * lane) =
          make_float2(t0[r], t1[r]);
  }
}

// ---------------------------------------------------------------------------
// K2: mu = sum_u (A+E)*nu/(1+A*E); masked softmax.
// grid 256 = jg*8 + b, 512 thr (8 waves). wave: jp = w>>2 (j-pair), q = w&3
// (i-quarter); lane owns 2 i. Per-u uniform operands {A0, A0*nu, A1, A1*nu}
// and nu are staged in LDS ONCE per block and read via ds_read_b128
// broadcast, double-buffered -- no s_load in the inner loop (round-5 fix).
// ---------------------------------------------------------------------------
__global__ __launch_bounds__(512) void attn_mu_softmax_kernel(
    const float* __restrict__ Et, const float* __restrict__ de_t,
    const float* __restrict__ nu, const int* __restrict__ mask,
    float* __restrict__ out) {
  __shared__ f32x4 Lp_s[2][U_];     // {A0, An0, A1, An1}  (8 KB)
  __shared__ f32x4 nv_s[U_ / 4];    // packed nu           (1 KB)
  __shared__ float mu_s[4][T_EN_];  // logits              (8 KB)

  const int tid  = threadIdx.x;
  const int lane = tid & 63;
  const int w    = __builtin_amdgcn_readfirstlane(tid >> 6);  // 0..7
  const int q    = w & 3;
  const int jp   = w >> 2;
  const int b    = blockIdx.x & 7;
  const int jg   = blockIdx.x >> 3;    // 0..31

  // ---- prologue: stage per-u uniform operands into LDS ----
  {
    const int u = tid & 255;
    const int p = tid >> 8;            // 0..1
    const int jA = jg * 4 + p * 2;
    const float A0 = de_t[(size_t)(b * T_DE_ + jA) * U_ + u];
    const float A1 = de_t[(size_t)(b * T_DE_ + jA + 1) * U_ + u];
    const float nv = nu[u];
    f32x4 L;
    L[0] = A0; L[1] = A0 * nv; L[2] = A1; L[3] = A1 * nv;
    Lp_s[p][u] = L;
    if (tid < 64) {
      const float4 t4 = *(const float4*)(nu + tid * 4);
      f32x4 n4; n4[0] = t4.x; n4[1] = t4.y; n4[2] = t4.z; n4[3] = t4.w;
      nv_s[tid] = n4;
    }
  }
  __syncthreads();

  const float* __restrict__ Eb = Et + (size_t)b * U_ * T_EN_ + q * 128 + lane * 2;

  float ac00 = 0.f, ac01 = 0.f, ac10 = 0.f, ac11 = 0.f;  // [jl][il]

  f32x4 La[8], Lb2[8], nva[2], nvb[2];
  float2 Ea[8], Eb2[8];

#define LDSL(LBUF, NBUF, U0)                                             \
  { _Pragma("unroll")                                                    \
    for (int e = 0; e < 8; ++e) LBUF[e] = Lp_s[jp][(U0) + e];            \
    NBUF[0] = nv_s[(U0) / 4];                                            \
    NBUF[1] = nv_s[(U0) / 4 + 1]; }
#define GL(EBUF, U0)                                                     \
  { _Pragma("unroll")                                                    \
    for (int e = 0; e < 8; ++e)                                          \
      EBUF[e] = *(const float2*)(Eb + (size_t)((U0) + e) * T_EN_); }
#define COMP(LBUF, NBUF, EBUF)                                           \
  { _Pragma("unroll")                                                    \
    for (int e = 0; e < 8; ++e) {                                        \
      const float nv  = NBUF[e >> 2][e & 3];                             \
      const float A0  = LBUF[e][0], An0 = LBUF[e][1];                    \
      const float A1  = LBUF[e][2], An1 = LBUF[e][3];                    \
      const float ex = EBUF[e].x, ey = EBUF[e].y;                        \
      ac00 = fmaf(fmaf(nv, ex, An0),                                     \
                  __builtin_amdgcn_rcpf(fmaf(A0, ex, 1.0f)), ac00);      \
      ac01 = fmaf(fmaf(nv, ey, An0),                                     \
                  __builtin_amdgcn_rcpf(fmaf(A0, ey, 1.0f)), ac01);      \
      ac10 = fmaf(fmaf(nv, ex, An1),                                     \
                  __builtin_amdgcn_rcpf(fmaf(A1, ex, 1.0f)), ac10);      \
      ac11 = fmaf(fmaf(nv, ey, An1),                                     \
                  __builtin_amdgcn_rcpf(fmaf(A1, ey, 1.0f)), ac11); } }

  LDSL(La, nva, 0)
  GL(Ea, 0)
  for (int u0 = 0; u0 < U_; u0 += 16) {
    LDSL(Lb2, nvb, u0 + 8)
    GL(Eb2, u0 + 8)
    COMP(La, nva, Ea)
    if (u0 + 16 < U_) {
      LDSL(La, nva, u0 + 16)
      GL(Ea, u0 + 16)
    }
    COMP(Lb2, nvb, Eb2)
  }
#undef LDSL
#undef GL
#undef COMP

  *(float2*)&mu_s[jp * 2 + 0][q * 128 + lane * 2] = make_float2(ac00, ac01);
  *(float2*)&mu_s[jp * 2 + 1][q * 128 + lane * 2] = make_float2(ac10, ac11);
  __syncthreads();

  // ---- masked softmax: waves 0..3, one j each ----
  if (w < 4) {
    const int jj = jg * 4 + w;
    float vals[8];
    float mx = -3.0e38f;
    #pragma unroll
    for (int k = 0; k < 8; ++k) {
      const int i = lane + 64 * k;
      const float mi = (float)mask[b * T_EN_ + i];
      const float v = fmaf(mi - 1.0f, 1.0e6f, mu_s[w][i]);
      vals[k] = v;
      mx = fmaxf(mx, v);
    }
    #pragma unroll
    for (int off = 32; off; off >>= 1) mx = fmaxf(mx, __shfl_xor(mx, off, 64));
    float sum = 0.0f;
    #pragma unroll
    for (int k = 0; k < 8; ++k) {
      const float e = __builtin_amdgcn_exp2f((vals[k] - mx) * L2E_);
      vals[k] = e;
      sum += e;
    }
    #pragma unroll
    for (int off = 32; off; off >>= 1) sum += __shfl_xor(sum, off, 64);
    const float inv = __builtin_amdgcn_rcpf(sum);
    float* op = out + (size_t)(b * T_DE_ + jj) * T_EN_;
    #pragma unroll
    for (int k = 0; k < 8; ++k) op[lane + 64 * k] = vals[k] * inv;
  }
}

// ---------------------------------------------------------------------------
extern "C" void kernel_launch(void* const* d_in, const int* in_sizes, int n_in,
                              void* d_out, int out_size, void* d_ws, size_t ws_size,
                              hipStream_t stream) {
  const float* en   = (const float*)d_in[0];   // [B, T_EN, D]
  const float* de   = (const float*)d_in[1];   // [B, T_DE, D]
  const int*   mask = (const int*)d_in[2];     // [B, T_EN]
  const float* w_en = (const float*)d_in[3];   // [D, U]
  const float* w_de = (const float*)d_in[4];   // [D, U]
  const float* nu   = (const float*)d_in[5];   // [U, 1]
  float* out = (float*)d_out;                  // [B, T_DE, T_EN]

  // ws layout
  float* Et   = (float*)d_ws;                  // [B][U][T_EN]  4 MB
  float* de_t = Et + (size_t)B_ * U_ * T_EN_;  // [B*T_DE][U]   1 MB
  short* p    = (short*)(de_t + (size_t)B_ * T_DE_ * U_);
  short* en_hi = p;                 p += 2097152;   // B*T_EN*D
  short* en_lo = p;                 p += 2097152;
  short* de_hi = p;                 p += 524288;    // B*T_DE*D
  short* de_lo = p;                 p += 524288;
  short* wen_hi = p;                p += 131072;    // D*U
  short* wen_lo = p;                p += 131072;
  short* wde_hi = p;                p += 131072;
  short* wde_lo = p;                p += 131072;
  const size_t need = (size_t)(1048576 + 262144) * 4 +
                      (size_t)(2 * 2097152 + 2 * 524288 + 4 * 131072) * 2;  // 16 MB

  if (ws_size >= need) {
    prepack_kernel<<<dim3(1408), 256, 0, stream>>>(
        en, de, w_en, w_de, en_hi, en_lo, de_hi, de_lo,
        wen_hi, wen_lo, wde_hi, wde_lo);
    mfma_proj_kernel<<<dim3(640), 256, 0, stream>>>(
        en_hi, en_lo, de_hi, de_lo, wen_hi, wen_lo, wde_hi, wde_lo, Et, de_t);
  } else {
    proj_tanh_fallback<<<dim3(320), 256, 0, stream>>>(en, de, w_en, w_de, Et, de_t);
  }
  attn_mu_softmax_kernel<<<dim3(256), 512, 0, stream>>>(Et, de_t, nu, mask, out);
}